// Round 4
// baseline (290.442 us; speedup 1.0000x reference)
//
#include <hip/hip_runtime.h>
#include <math.h>

// GraphSAGE (mean) + GCN + softmax, f32 semantics via split-bf16 MFMA.
// Fully fused: CSR gather -> GEMM1 -> GEMM2 in one kernel.
// N=100000, E=625000, D_IN=D_H=128, D_OUT=64 (derived from in_sizes).

#define DIN 128
#define DH  128
#define DOUT 64
#define U_STR 264   // 256 + 8 pad (ushort): 2-way bank alias (free)
#define H_STR 136   // 128 + 8 pad (ushort): 2-way bank alias (free)

typedef __attribute__((ext_vector_type(8))) short short8v;   // 8 bf16
typedef __attribute__((ext_vector_type(4))) float float4v;   // MFMA acc

// split f32 -> bf16 hi (truncate) + bf16 lo (residual, truncate)
__device__ __forceinline__ void splitf(float a, unsigned short& hi, unsigned short& lo) {
    unsigned ai = __float_as_uint(a);
    hi = (unsigned short)(ai >> 16);
    float r = a - __uint_as_float(ai & 0xffff0000u);
    lo = (unsigned short)(__float_as_uint(r) >> 16);
}

// ---------------- edge-index dtype detection (int64 vs int32) --------------
__global__ void detect_idx_kernel(const void* ei, int twoE, int* flag) {
    __shared__ int ok;
    if (threadIdx.x == 0) ok = 1;
    __syncthreads();
    const int* p = (const int*)ei;
    for (int i = threadIdx.x; i < 512; i += blockDim.x) {
        long long pos = 1 + ((long long)i * (long long)(twoE - 2)) / 512;
        pos |= 1;
        if (pos < twoE && p[pos] != 0) ok = 0;
    }
    __syncthreads();
    if (threadIdx.x == 0) *flag = ok;  // 1 => int64, 0 => int32
}

__device__ __forceinline__ void load_edge(const void* ei, int e, int E, int is64,
                                          int& s, int& d) {
    if (is64) {
        const long long* p = (const long long*)ei;
        s = (int)p[e];
        d = (int)p[E + e];
    } else {
        const int* p = (const int*)ei;
        s = p[e];
        d = p[E + e];
    }
}

// ---------------- weight split to bf16 hi/lo -------------------------------
__global__ void prep_weights_split(const float* __restrict__ Wl, const float* __restrict__ Wr,
                                   const float* __restrict__ Wg,
                                   unsigned short* __restrict__ WcH, unsigned short* __restrict__ WcL,
                                   unsigned short* __restrict__ WgH, unsigned short* __restrict__ WgL) {
    int idx = blockIdx.x * 256 + threadIdx.x;
    if (idx < 128 * 256) {
        int o = idx >> 8, k = idx & 255;
        float v = (k < 128) ? Wl[o * 128 + k] : Wr[o * 128 + (k - 128)];
        splitf(v, WcH[idx], WcL[idx]);
    } else {
        int j = idx - 128 * 256;
        if (j < 64 * 128) splitf(Wg[j], WgH[j], WgL[j]);
    }
}

// ---------------- CSR build -----------------------------------------------
__global__ void count_deg(const void* __restrict__ ei, const int* __restrict__ flag,
                          int* __restrict__ deg, int E) {
    int e = blockIdx.x * 256 + threadIdx.x;
    if (e >= E) return;
    int s, d;
    load_edge(ei, e, E, *flag, s, d);
    atomicAdd(&deg[d], 1);
}

__global__ void scan_partial(const int* __restrict__ deg, int* __restrict__ partial, int N) {
    int base = blockIdx.x * 1024;
    int t = threadIdx.x;
    int s = 0;
    for (int i = t; i < 1024; i += 256) {
        int g = base + i;
        if (g < N) s += deg[g];
    }
    __shared__ int sh[256];
    sh[t] = s;
    __syncthreads();
    for (int off = 128; off; off >>= 1) {
        if (t < off) sh[t] += sh[t + off];
        __syncthreads();
    }
    if (t == 0) partial[blockIdx.x] = sh[0];
}

__global__ void scan_offsets(int* partial, int nblk, int* rowptr, int N, int E) {
    if (threadIdx.x == 0 && blockIdx.x == 0) {
        int run = 0;
        for (int i = 0; i < nblk; ++i) {
            int v = partial[i];
            partial[i] = run;
            run += v;
        }
        rowptr[N] = E;
    }
}

__global__ void scan_final(const int* __restrict__ deg, const int* __restrict__ partial,
                           int* __restrict__ rowptr, int* __restrict__ cursor,
                           float* __restrict__ dinv, int N) {
    int base = blockIdx.x * 1024;
    int t = threadIdx.x;
    int i0 = base + t * 4;
    int v[4];
    int s = 0;
#pragma unroll
    for (int j = 0; j < 4; ++j) {
        int g = i0 + j;
        v[j] = (g < N) ? deg[g] : 0;
        s += v[j];
    }
    __shared__ int sh[256];
    sh[t] = s;
    __syncthreads();
    for (int off = 1; off < 256; off <<= 1) {
        int val = (t >= off) ? sh[t - off] : 0;
        __syncthreads();
        sh[t] += val;
        __syncthreads();
    }
    int pre = sh[t] - s + partial[blockIdx.x];
#pragma unroll
    for (int j = 0; j < 4; ++j) {
        int g = i0 + j;
        if (g < N) {
            rowptr[g] = pre;
            cursor[g] = pre;
            dinv[g] = rsqrtf((float)v[j] + 1.0f);
            pre += v[j];
        }
    }
}

__global__ void fill_csr(const void* __restrict__ ei, const int* __restrict__ flag,
                         int* __restrict__ cursor, int* __restrict__ col, int E) {
    int e = blockIdx.x * 256 + threadIdx.x;
    if (e >= E) return;
    int s, d;
    load_edge(ei, e, E, *flag, s, d);
    int pos = atomicAdd(&cursor[d], 1);
    col[pos] = s;
}

// ---------------- fused: gather mean -> GEMM1 -> GEMM2 ---------------------
// 32 nodes/block, 256 threads (4 waves). Each wave gathers 8 nodes
// (2 neighbors per iteration: half-waves, float4/lane), splits to bf16 LDS,
// then: h = relu([mean|x] @ Wcat^T + bl) in LDS; hw = h @ Wg^T -> dense N x 64.
__global__ __launch_bounds__(256) void sage_fused(
    const int* __restrict__ rowptr, const int* __restrict__ col,
    const float* __restrict__ x,
    const unsigned short* __restrict__ WcH, const unsigned short* __restrict__ WcL,
    const unsigned short* __restrict__ WgH, const unsigned short* __restrict__ WgL,
    const float* __restrict__ bl, float* __restrict__ hw, int N)
{
    __shared__ unsigned short usH[32 * U_STR];
    __shared__ unsigned short usL[32 * U_STR];
    __shared__ unsigned short hsH[32 * H_STR];
    __shared__ unsigned short hsL[32 * H_STR];
    const int tid = threadIdx.x;
    const int n0 = blockIdx.x * 32;
    const int wave = tid >> 6;
    const int lane = tid & 63;
    const int half = lane >> 5;   // neighbor parity
    const int hl = lane & 31;     // col group

    // ---- Phase A: gather mean + stage [mean|x] as bf16 hi/lo
    for (int i = 0; i < 8; ++i) {
        int row = wave * 8 + i;
        int node = n0 + row;
        int nc = node < N ? node : N - 1;
        int beg = rowptr[nc], end = rowptr[nc + 1];
        float4 acc = make_float4(0.f, 0.f, 0.f, 0.f);
        int e = beg;
        for (; e + 3 < end; e += 4) {   // two pairs in flight
            int sA = col[e + half];
            int sB = col[e + 2 + half];
            float4 vA = *(const float4*)(x + (size_t)sA * DIN + hl * 4);
            float4 vB = *(const float4*)(x + (size_t)sB * DIN + hl * 4);
            acc.x += vA.x + vB.x;
            acc.y += vA.y + vB.y;
            acc.z += vA.z + vB.z;
            acc.w += vA.w + vB.w;
        }
        for (; e + 1 < end; e += 2) {
            int sA = col[e + half];
            float4 vA = *(const float4*)(x + (size_t)sA * DIN + hl * 4);
            acc.x += vA.x;
            acc.y += vA.y;
            acc.z += vA.z;
            acc.w += vA.w;
        }
        if (e < end && half == 0) {
            int sA = col[e];
            float4 vA = *(const float4*)(x + (size_t)sA * DIN + hl * 4);
            acc.x += vA.x;
            acc.y += vA.y;
            acc.z += vA.z;
            acc.w += vA.w;
        }
        acc.x += __shfl_xor(acc.x, 32, 64);
        acc.y += __shfl_xor(acc.y, 32, 64);
        acc.z += __shfl_xor(acc.z, 32, 64);
        acc.w += __shfl_xor(acc.w, 32, 64);
        float invd = (end > beg) ? 1.0f / (float)(end - beg) : 0.f;
        if (half == 0) {
            int base = row * U_STR + hl * 4;
            splitf(acc.x * invd, usH[base + 0], usL[base + 0]);
            splitf(acc.y * invd, usH[base + 1], usL[base + 1]);
            splitf(acc.z * invd, usH[base + 2], usL[base + 2]);
            splitf(acc.w * invd, usH[base + 3], usL[base + 3]);
        }
        // self x -> cols 128..255 (all 64 lanes, float2 each)
        float2 xv = *(const float2*)(x + (size_t)nc * DIN + lane * 2);
        int b2 = row * U_STR + 128 + lane * 2;
        splitf(xv.x, usH[b2 + 0], usL[b2 + 0]);
        splitf(xv.y, usH[b2 + 1], usL[b2 + 1]);
    }
    __syncthreads();

    const int lrow = lane & 15;        // A-row / B-out / D-col
    const int lk8  = (lane >> 4) << 3; // k base within K=32 step
    const int qr   = (lane >> 4) << 2; // D-row base

    // ---- GEMM1: h[32x128] = u[32x256] @ Wcat^T, wave -> cols [wave*32,+32)
    float4v acc00 = {0.f, 0.f, 0.f, 0.f};
    float4v acc01 = {0.f, 0.f, 0.f, 0.f};
    float4v acc10 = {0.f, 0.f, 0.f, 0.f};
    float4v acc11 = {0.f, 0.f, 0.f, 0.f};
    const int o0 = wave * 32 + lrow;
    const int o1 = o0 + 16;

#pragma unroll
    for (int ks = 0; ks < 8; ++ks) {
        int kb = ks * 32 + lk8;
        short8v a0h = *(const short8v*)&usH[lrow * U_STR + kb];
        short8v a0l = *(const short8v*)&usL[lrow * U_STR + kb];
        short8v a1h = *(const short8v*)&usH[(16 + lrow) * U_STR + kb];
        short8v a1l = *(const short8v*)&usL[(16 + lrow) * U_STR + kb];
        short8v b0h = *(const short8v*)(WcH + o0 * 256 + kb);
        short8v b0l = *(const short8v*)(WcL + o0 * 256 + kb);
        short8v b1h = *(const short8v*)(WcH + o1 * 256 + kb);
        short8v b1l = *(const short8v*)(WcL + o1 * 256 + kb);
        acc00 = __builtin_amdgcn_mfma_f32_16x16x32_bf16(a0h, b0h, acc00, 0, 0, 0);
        acc00 = __builtin_amdgcn_mfma_f32_16x16x32_bf16(a0h, b0l, acc00, 0, 0, 0);
        acc00 = __builtin_amdgcn_mfma_f32_16x16x32_bf16(a0l, b0h, acc00, 0, 0, 0);
        acc01 = __builtin_amdgcn_mfma_f32_16x16x32_bf16(a0h, b1h, acc01, 0, 0, 0);
        acc01 = __builtin_amdgcn_mfma_f32_16x16x32_bf16(a0h, b1l, acc01, 0, 0, 0);
        acc01 = __builtin_amdgcn_mfma_f32_16x16x32_bf16(a0l, b1h, acc01, 0, 0, 0);
        acc10 = __builtin_amdgcn_mfma_f32_16x16x32_bf16(a1h, b0h, acc10, 0, 0, 0);
        acc10 = __builtin_amdgcn_mfma_f32_16x16x32_bf16(a1h, b0l, acc10, 0, 0, 0);
        acc10 = __builtin_amdgcn_mfma_f32_16x16x32_bf16(a1l, b0h, acc10, 0, 0, 0);
        acc11 = __builtin_amdgcn_mfma_f32_16x16x32_bf16(a1h, b1h, acc11, 0, 0, 0);
        acc11 = __builtin_amdgcn_mfma_f32_16x16x32_bf16(a1h, b1l, acc11, 0, 0, 0);
        acc11 = __builtin_amdgcn_mfma_f32_16x16x32_bf16(a1l, b1h, acc11, 0, 0, 0);
    }

    // ---- bias + ReLU + split h into LDS
    {
        float bb0 = bl[wave * 32 + lrow];
        float bb1 = bl[wave * 32 + 16 + lrow];
        int c0 = wave * 32 + lrow;
        int c1 = c0 + 16;
#pragma unroll
        for (int q = 0; q < 4; ++q) {
            int r0 = qr + q;
            int r1 = 16 + qr + q;
            float v;
            v = fmaxf(acc00[q] + bb0, 0.f); splitf(v, hsH[r0 * H_STR + c0], hsL[r0 * H_STR + c0]);
            v = fmaxf(acc01[q] + bb1, 0.f); splitf(v, hsH[r0 * H_STR + c1], hsL[r0 * H_STR + c1]);
            v = fmaxf(acc10[q] + bb0, 0.f); splitf(v, hsH[r1 * H_STR + c0], hsL[r1 * H_STR + c0]);
            v = fmaxf(acc11[q] + bb1, 0.f); splitf(v, hsH[r1 * H_STR + c1], hsL[r1 * H_STR + c1]);
        }
    }
    __syncthreads();

    // ---- GEMM2: hw[32x64] = h[32x128] @ Wg^T, wave -> col-tile `wave`
    float4v acc2_0 = {0.f, 0.f, 0.f, 0.f};
    float4v acc2_1 = {0.f, 0.f, 0.f, 0.f};
    const int og = wave * 16 + lrow;
#pragma unroll
    for (int ks = 0; ks < 4; ++ks) {
        int kb = ks * 32 + lk8;
        short8v a0h = *(const short8v*)&hsH[lrow * H_STR + kb];
        short8v a0l = *(const short8v*)&hsL[lrow * H_STR + kb];
        short8v a1h = *(const short8v*)&hsH[(16 + lrow) * H_STR + kb];
        short8v a1l = *(const short8v*)&hsL[(16 + lrow) * H_STR + kb];
        short8v bh = *(const short8v*)(WgH + og * 128 + kb);
        short8v bl8 = *(const short8v*)(WgL + og * 128 + kb);
        acc2_0 = __builtin_amdgcn_mfma_f32_16x16x32_bf16(a0h, bh, acc2_0, 0, 0, 0);
        acc2_0 = __builtin_amdgcn_mfma_f32_16x16x32_bf16(a0h, bl8, acc2_0, 0, 0, 0);
        acc2_0 = __builtin_amdgcn_mfma_f32_16x16x32_bf16(a0l, bh, acc2_0, 0, 0, 0);
        acc2_1 = __builtin_amdgcn_mfma_f32_16x16x32_bf16(a1h, bh, acc2_1, 0, 0, 0);
        acc2_1 = __builtin_amdgcn_mfma_f32_16x16x32_bf16(a1h, bl8, acc2_1, 0, 0, 0);
        acc2_1 = __builtin_amdgcn_mfma_f32_16x16x32_bf16(a1l, bh, acc2_1, 0, 0, 0);
    }

    // ---- write hw dense N x 64
#pragma unroll
    for (int q = 0; q < 4; ++q) {
        int node0 = n0 + qr + q;
        int node1 = n0 + 16 + qr + q;
        if (node0 < N) hw[(size_t)node0 * DOUT + og] = acc2_0[q];
        if (node1 < N) hw[(size_t)node1 * DOUT + og] = acc2_1[q];
    }
}

// ---------------- gather GCN + fused softmax (one wave per node) -----------
// 2 neighbors per iteration (half-waves, float2/lane over 64 cols).
__global__ void gather_gcn_softmax(const int* __restrict__ rowptr, const int* __restrict__ col,
                                   const float* __restrict__ hw, const float* __restrict__ dinv,
                                   const float* __restrict__ bg,
                                   float* __restrict__ out, float* __restrict__ soft, int N) {
    int node = blockIdx.x * 4 + (threadIdx.x >> 6);
    if (node >= N) return;
    int lane = threadIdx.x & 63;
    int half = lane >> 5;
    int hl = lane & 31;
    int beg = rowptr[node], end = rowptr[node + 1];
    float2 acc = make_float2(0.f, 0.f);
    int e = beg;
    for (; e + 3 < end; e += 4) {
        int sA = col[e + half];
        int sB = col[e + 2 + half];
        float wA = dinv[sA], wB = dinv[sB];
        float2 vA = *(const float2*)(hw + (size_t)sA * DOUT + hl * 2);
        float2 vB = *(const float2*)(hw + (size_t)sB * DOUT + hl * 2);
        acc.x += wA * vA.x + wB * vB.x;
        acc.y += wA * vA.y + wB * vB.y;
    }
    for (; e + 1 < end; e += 2) {
        int sA = col[e + half];
        float wA = dinv[sA];
        float2 vA = *(const float2*)(hw + (size_t)sA * DOUT + hl * 2);
        acc.x += wA * vA.x;
        acc.y += wA * vA.y;
    }
    if (e < end && half == 0) {
        int sA = col[e];
        float wA = dinv[sA];
        float2 vA = *(const float2*)(hw + (size_t)sA * DOUT + hl * 2);
        acc.x += wA * vA.x;
        acc.y += wA * vA.y;
    }
    acc.x += __shfl_xor(acc.x, 32, 64);
    acc.y += __shfl_xor(acc.y, 32, 64);

    float di = dinv[node];
    float2 selfv = *(const float2*)(hw + (size_t)node * DOUT + hl * 2);
    float v0 = di * acc.x + di * di * selfv.x + bg[hl * 2 + 0];
    float v1 = di * acc.y + di * di * selfv.y + bg[hl * 2 + 1];

    // softmax over 64 cols: 2 cols/lane on 32 lanes (both halves redundant)
    float m = fmaxf(v0, v1);
#pragma unroll
    for (int mask = 16; mask; mask >>= 1) m = fmaxf(m, __shfl_xor(m, mask, 64));
    float e0 = __expf(v0 - m), e1 = __expf(v1 - m);
    float s = e0 + e1;
#pragma unroll
    for (int mask = 16; mask; mask >>= 1) s += __shfl_xor(s, mask, 64);
    if (half == 0) {
        float2 ov = make_float2(v0, v1);
        float2 sv = make_float2(e0 / s, e1 / s);
        *(float2*)(out + (size_t)node * DOUT + hl * 2) = ov;
        *(float2*)(soft + (size_t)node * DOUT + hl * 2) = sv;
    }
}

// ---------------------------------------------------------------------------
extern "C" void kernel_launch(void* const* d_in, const int* in_sizes, int n_in,
                              void* d_out, int out_size, void* d_ws, size_t ws_size,
                              hipStream_t stream) {
    const float* x  = (const float*)d_in[0];
    const void*  ei = d_in[1];
    const float* Wl = (const float*)d_in[2];
    const float* bl = (const float*)d_in[3];
    const float* Wr = (const float*)d_in[4];
    const float* Wg = (const float*)d_in[5];
    const float* bg = (const float*)d_in[6];
    const int N = in_sizes[0] / DIN;
    const int E = in_sizes[1] / 2;
    float* out = (float*)d_out;

    char* ws = (char*)d_ws;
    size_t off = 0;
    auto alloc = [&](size_t bytes) {
        void* p = ws + off;
        off += (bytes + 255) / 256 * 256;
        return p;
    };
    int*   flag    = (int*)alloc(4);
    int*   deg     = (int*)alloc((size_t)N * 4);
    float* dinv    = (float*)alloc((size_t)N * 4);
    int*   rowptr  = (int*)alloc((size_t)(N + 1) * 4);
    int*   cursor  = (int*)alloc((size_t)N * 4);
    int*   colv    = (int*)alloc((size_t)E * 4);
    int*   partial = (int*)alloc(1024 * 4);
    unsigned short* WcH = (unsigned short*)alloc(128 * 256 * 2);
    unsigned short* WcL = (unsigned short*)alloc(128 * 256 * 2);
    unsigned short* WgH = (unsigned short*)alloc(64 * 128 * 2);
    unsigned short* WgL = (unsigned short*)alloc(64 * 128 * 2);
    float* hw      = (float*)alloc((size_t)N * DOUT * 4);
    (void)ws_size; (void)n_in; (void)out_size;

    float* soft = out + (size_t)N * DOUT;

    const int nblk = (N + 1023) / 1024;

    hipMemsetAsync(deg, 0, (size_t)N * 4, stream);

    detect_idx_kernel<<<1, 256, 0, stream>>>(ei, 2 * E, flag);
    prep_weights_split<<<160, 256, 0, stream>>>(Wl, Wr, Wg, WcH, WcL, WgH, WgL);
    count_deg<<<(E + 255) / 256, 256, 0, stream>>>(ei, flag, deg, E);
    scan_partial<<<nblk, 256, 0, stream>>>(deg, partial, N);
    scan_offsets<<<1, 64, 0, stream>>>(partial, nblk, rowptr, N, E);
    scan_final<<<nblk, 256, 0, stream>>>(deg, partial, rowptr, cursor, dinv, N);
    fill_csr<<<(E + 255) / 256, 256, 0, stream>>>(ei, flag, cursor, colv, E);
    sage_fused<<<(N + 31) / 32, 256, 0, stream>>>(rowptr, colv, x, WcH, WcL, WgH, WgL, bl, hw, N);
    gather_gcn_softmax<<<(N + 3) / 4, 256, 0, stream>>>(rowptr, colv, hw, dinv, bg, out, soft, N);
}

// Round 5
// 273.345 us; speedup vs baseline: 1.0625x; 1.0625x over previous
//
#include <hip/hip_runtime.h>
#include <math.h>

// GraphSAGE (mean) + GCN + softmax, f32 semantics via split-bf16 MFMA.
// CSR gather (bf16 x) -> split-bf16 MFMA GEMM -> CSR gather GCN + softmax.
// N=100000, E=625000, D_IN=D_H=128, D_OUT=64 (derived from in_sizes).

#define DIN 128
#define DH  128
#define DOUT 64
#define U_STR 264   // 256 + 8 pad (ushort): 2-way bank alias (free)
#define L_STR 136   // 128 + 8 pad
#define H_STR 136   // 128 + 8 pad

typedef __attribute__((ext_vector_type(8))) short short8v;            // 8 bf16
typedef __attribute__((ext_vector_type(4))) float float4v;            // MFMA acc
typedef __attribute__((ext_vector_type(4))) unsigned short ushort4v;  // 4 bf16

// split f32 -> bf16 hi (truncate) + bf16 lo (residual, truncate)
__device__ __forceinline__ void splitf(float a, unsigned short& hi, unsigned short& lo) {
    unsigned ai = __float_as_uint(a);
    hi = (unsigned short)(ai >> 16);
    float r = a - __uint_as_float(ai & 0xffff0000u);
    lo = (unsigned short)(__float_as_uint(r) >> 16);
}

// f32 -> bf16 round-to-nearest-even
__device__ __forceinline__ unsigned short f2bf_rne(float f) {
    unsigned u = __float_as_uint(f);
    return (unsigned short)((u + 0x7fffu + ((u >> 16) & 1u)) >> 16);
}

__device__ __forceinline__ float bf2f(unsigned short u) {
    return __uint_as_float(((unsigned)u) << 16);
}

// ---------------- edge-index dtype detection (int64 vs int32) --------------
__global__ void detect_idx_kernel(const void* ei, int twoE, int* flag) {
    __shared__ int ok;
    if (threadIdx.x == 0) ok = 1;
    __syncthreads();
    const int* p = (const int*)ei;
    for (int i = threadIdx.x; i < 512; i += blockDim.x) {
        long long pos = 1 + ((long long)i * (long long)(twoE - 2)) / 512;
        pos |= 1;
        if (pos < twoE && p[pos] != 0) ok = 0;
    }
    __syncthreads();
    if (threadIdx.x == 0) *flag = ok;  // 1 => int64, 0 => int32
}

__device__ __forceinline__ void load_edge(const void* ei, int e, int E, int is64,
                                          int& s, int& d) {
    if (is64) {
        const long long* p = (const long long*)ei;
        s = (int)p[e];
        d = (int)p[E + e];
    } else {
        const int* p = (const int*)ei;
        s = p[e];
        d = p[E + e];
    }
}

// ---------------- prep: weight split + x -> bf16 ---------------------------
__global__ void prep_all(const float* __restrict__ Wl, const float* __restrict__ Wr,
                         const float* __restrict__ Wg,
                         unsigned short* __restrict__ WcH, unsigned short* __restrict__ WcL,
                         unsigned short* __restrict__ WgH, unsigned short* __restrict__ WgL,
                         const float* __restrict__ x, unsigned short* __restrict__ xbf,
                         size_t xElems) {
    size_t idx = (size_t)blockIdx.x * 256 + threadIdx.x;
    if (idx < 128 * 256) {
        int o = (int)(idx >> 8), k = (int)(idx & 255);
        float v = (k < 128) ? Wl[o * 128 + k] : Wr[o * 128 + (k - 128)];
        unsigned short h, l;
        splitf(v, h, l);
        WcH[idx] = h; WcL[idx] = l;
    } else if (idx < 128 * 256 + 64 * 128) {
        size_t j = idx - 128 * 256;
        unsigned short h, l;
        splitf(Wg[j], h, l);
        WgH[j] = h; WgL[j] = l;
    } else {
        size_t j = (idx - (128 * 256 + 64 * 128)) * 4;
        if (j < xElems) {
            float4 v = *(const float4*)(x + j);
            ushort4v o;
            o[0] = f2bf_rne(v.x);
            o[1] = f2bf_rne(v.y);
            o[2] = f2bf_rne(v.z);
            o[3] = f2bf_rne(v.w);
            *(ushort4v*)(xbf + j) = o;
        }
    }
}

// ---------------- CSR build -----------------------------------------------
__global__ void count_deg(const void* __restrict__ ei, const int* __restrict__ flag,
                          int* __restrict__ deg, int E) {
    int e = blockIdx.x * 256 + threadIdx.x;
    if (e >= E) return;
    int s, d;
    load_edge(ei, e, E, *flag, s, d);
    atomicAdd(&deg[d], 1);
}

__global__ void scan_partial(const int* __restrict__ deg, int* __restrict__ partial, int N) {
    int base = blockIdx.x * 1024;
    int t = threadIdx.x;
    int s = 0;
    for (int i = t; i < 1024; i += 256) {
        int g = base + i;
        if (g < N) s += deg[g];
    }
    __shared__ int sh[256];
    sh[t] = s;
    __syncthreads();
    for (int off = 128; off; off >>= 1) {
        if (t < off) sh[t] += sh[t + off];
        __syncthreads();
    }
    if (t == 0) partial[blockIdx.x] = sh[0];
}

__global__ void scan_offsets(int* partial, int nblk, int* rowptr, int N, int E) {
    if (threadIdx.x == 0 && blockIdx.x == 0) {
        int run = 0;
        for (int i = 0; i < nblk; ++i) {
            int v = partial[i];
            partial[i] = run;
            run += v;
        }
        rowptr[N] = E;
    }
}

__global__ void scan_final(const int* __restrict__ deg, const int* __restrict__ partial,
                           int* __restrict__ rowptr, int* __restrict__ cursor,
                           float* __restrict__ dinv, int N) {
    int base = blockIdx.x * 1024;
    int t = threadIdx.x;
    int i0 = base + t * 4;
    int v[4];
    int s = 0;
#pragma unroll
    for (int j = 0; j < 4; ++j) {
        int g = i0 + j;
        v[j] = (g < N) ? deg[g] : 0;
        s += v[j];
    }
    __shared__ int sh[256];
    sh[t] = s;
    __syncthreads();
    for (int off = 1; off < 256; off <<= 1) {
        int val = (t >= off) ? sh[t - off] : 0;
        __syncthreads();
        sh[t] += val;
        __syncthreads();
    }
    int pre = sh[t] - s + partial[blockIdx.x];
#pragma unroll
    for (int j = 0; j < 4; ++j) {
        int g = i0 + j;
        if (g < N) {
            rowptr[g] = pre;
            cursor[g] = pre;
            dinv[g] = rsqrtf((float)v[j] + 1.0f);
            pre += v[j];
        }
    }
}

__global__ void fill_csr(const void* __restrict__ ei, const int* __restrict__ flag,
                         int* __restrict__ cursor, int* __restrict__ col, int E) {
    int e = blockIdx.x * 256 + threadIdx.x;
    if (e >= E) return;
    int s, d;
    load_edge(ei, e, E, *flag, s, d);
    int pos = atomicAdd(&cursor[d], 1);
    col[pos] = s;
}

// ---------------- gather mean from bf16 x (one wave per node) --------------
// 2 neighbors in flight per pair (half-waves, ushort4/lane = full 256 B row).
__global__ void gather_mean(const int* __restrict__ rowptr, const int* __restrict__ col,
                            const unsigned short* __restrict__ xbf,
                            unsigned short* __restrict__ meanH,
                            unsigned short* __restrict__ meanL, int N) {
    int node = blockIdx.x * 4 + (threadIdx.x >> 6);
    if (node >= N) return;
    int lane = threadIdx.x & 63;
    int half = lane >> 5;
    int hl = lane & 31;
    int beg = rowptr[node], end = rowptr[node + 1];
    float a0 = 0.f, a1 = 0.f, a2 = 0.f, a3 = 0.f;
    int e = beg;
    for (; e + 3 < end; e += 4) {
        int sA = col[e + half];
        int sB = col[e + 2 + half];
        ushort4v vA = *(const ushort4v*)(xbf + (size_t)sA * DIN + hl * 4);
        ushort4v vB = *(const ushort4v*)(xbf + (size_t)sB * DIN + hl * 4);
        a0 += bf2f(vA[0]) + bf2f(vB[0]);
        a1 += bf2f(vA[1]) + bf2f(vB[1]);
        a2 += bf2f(vA[2]) + bf2f(vB[2]);
        a3 += bf2f(vA[3]) + bf2f(vB[3]);
    }
    for (; e + 1 < end; e += 2) {
        int sA = col[e + half];
        ushort4v vA = *(const ushort4v*)(xbf + (size_t)sA * DIN + hl * 4);
        a0 += bf2f(vA[0]);
        a1 += bf2f(vA[1]);
        a2 += bf2f(vA[2]);
        a3 += bf2f(vA[3]);
    }
    if (e < end && half == 0) {
        int sA = col[e];
        ushort4v vA = *(const ushort4v*)(xbf + (size_t)sA * DIN + hl * 4);
        a0 += bf2f(vA[0]);
        a1 += bf2f(vA[1]);
        a2 += bf2f(vA[2]);
        a3 += bf2f(vA[3]);
    }
    a0 += __shfl_xor(a0, 32, 64);
    a1 += __shfl_xor(a1, 32, 64);
    a2 += __shfl_xor(a2, 32, 64);
    a3 += __shfl_xor(a3, 32, 64);
    if (half == 0) {
        float invd = (end > beg) ? 1.0f / (float)(end - beg) : 0.f;
        ushort4v H, L;
        unsigned short h, l;
        splitf(a0 * invd, h, l); H[0] = h; L[0] = l;
        splitf(a1 * invd, h, l); H[1] = h; L[1] = l;
        splitf(a2 * invd, h, l); H[2] = h; L[2] = l;
        splitf(a3 * invd, h, l); H[3] = h; L[3] = l;
        *(ushort4v*)(meanH + (size_t)node * DIN + hl * 4) = H;
        *(ushort4v*)(meanL + (size_t)node * DIN + hl * 4) = L;
    }
}

// ---------------- GEMM: h = relu([mean|x]@Wcat^T + bl); hw = h@Wg^T --------
// 32 nodes/block, 256 threads (4 waves). A-side staged as ushorts (no splitf).
// Upper-K half (x region) has zero lo -> skip al*bh MFMAs there.
// NOTE: hw aliases meanL byte-exactly per node-row (each block reads its own
// 32 meanL rows during staging, then writes the same 32 hw rows afterwards).
__global__ __launch_bounds__(256) void sage_gemm(
    const unsigned short* __restrict__ meanH, const unsigned short* __restrict__ meanL,
    const unsigned short* __restrict__ xbf,
    const unsigned short* __restrict__ WcH, const unsigned short* __restrict__ WcL,
    const unsigned short* __restrict__ WgH, const unsigned short* __restrict__ WgL,
    const float* __restrict__ bl, float* __restrict__ hw, int N)
{
    __shared__ unsigned short usH[32 * U_STR];
    __shared__ unsigned short usL[32 * L_STR];
    __shared__ unsigned short hsH[32 * H_STR];
    __shared__ unsigned short hsL[32 * H_STR];
    const int tid = threadIdx.x;
    const int n0 = blockIdx.x * 32;

    // ---- stage A-side: usH = [meanH | xbf], usL = meanL (cols 0..127)
    for (int idx = tid; idx < 32 * 64; idx += 256) {
        int n = idx >> 6;
        int c4 = (idx & 63) << 2;
        int node = n0 + n;
        if (node >= N) node = N - 1;
        ushort4v v = (c4 < 128)
                         ? *(const ushort4v*)(meanH + (size_t)node * DIN + c4)
                         : *(const ushort4v*)(xbf + (size_t)node * DIN + (c4 - 128));
        *(ushort4v*)(usH + n * U_STR + c4) = v;
    }
    for (int idx = tid; idx < 32 * 32; idx += 256) {
        int n = idx >> 5;
        int c4 = (idx & 31) << 2;
        int node = n0 + n;
        if (node >= N) node = N - 1;
        ushort4v v = *(const ushort4v*)(meanL + (size_t)node * DIN + c4);
        *(ushort4v*)(usL + n * L_STR + c4) = v;
    }
    __syncthreads();

    const int wave = tid >> 6;
    const int lane = tid & 63;
    const int lrow = lane & 15;        // A-row / B-out / D-col
    const int lk8  = (lane >> 4) << 3; // k base within K=32 step
    const int qr   = (lane >> 4) << 2; // D-row base

    float4v acc00 = {0.f, 0.f, 0.f, 0.f};
    float4v acc01 = {0.f, 0.f, 0.f, 0.f};
    float4v acc10 = {0.f, 0.f, 0.f, 0.f};
    float4v acc11 = {0.f, 0.f, 0.f, 0.f};
    const int o0 = wave * 32 + lrow;
    const int o1 = o0 + 16;

    // ---- GEMM1 lower K (mean part, hi/lo A): 3 MFMA per acc per ks
#pragma unroll
    for (int ks = 0; ks < 4; ++ks) {
        int kb = ks * 32 + lk8;
        short8v a0h = *(const short8v*)&usH[lrow * U_STR + kb];
        short8v a0l = *(const short8v*)&usL[lrow * L_STR + kb];
        short8v a1h = *(const short8v*)&usH[(16 + lrow) * U_STR + kb];
        short8v a1l = *(const short8v*)&usL[(16 + lrow) * L_STR + kb];
        short8v b0h = *(const short8v*)(WcH + o0 * 256 + kb);
        short8v b0l = *(const short8v*)(WcL + o0 * 256 + kb);
        short8v b1h = *(const short8v*)(WcH + o1 * 256 + kb);
        short8v b1l = *(const short8v*)(WcL + o1 * 256 + kb);
        acc00 = __builtin_amdgcn_mfma_f32_16x16x32_bf16(a0h, b0h, acc00, 0, 0, 0);
        acc00 = __builtin_amdgcn_mfma_f32_16x16x32_bf16(a0h, b0l, acc00, 0, 0, 0);
        acc00 = __builtin_amdgcn_mfma_f32_16x16x32_bf16(a0l, b0h, acc00, 0, 0, 0);
        acc01 = __builtin_amdgcn_mfma_f32_16x16x32_bf16(a0h, b1h, acc01, 0, 0, 0);
        acc01 = __builtin_amdgcn_mfma_f32_16x16x32_bf16(a0h, b1l, acc01, 0, 0, 0);
        acc01 = __builtin_amdgcn_mfma_f32_16x16x32_bf16(a0l, b1h, acc01, 0, 0, 0);
        acc10 = __builtin_amdgcn_mfma_f32_16x16x32_bf16(a1h, b0h, acc10, 0, 0, 0);
        acc10 = __builtin_amdgcn_mfma_f32_16x16x32_bf16(a1h, b0l, acc10, 0, 0, 0);
        acc10 = __builtin_amdgcn_mfma_f32_16x16x32_bf16(a1l, b0h, acc10, 0, 0, 0);
        acc11 = __builtin_amdgcn_mfma_f32_16x16x32_bf16(a1h, b1h, acc11, 0, 0, 0);
        acc11 = __builtin_amdgcn_mfma_f32_16x16x32_bf16(a1h, b1l, acc11, 0, 0, 0);
        acc11 = __builtin_amdgcn_mfma_f32_16x16x32_bf16(a1l, b1h, acc11, 0, 0, 0);
    }
    // ---- GEMM1 upper K (x part, zero A-lo): 2 MFMA per acc per ks
#pragma unroll
    for (int ks = 4; ks < 8; ++ks) {
        int kb = ks * 32 + lk8;
        short8v a0h = *(const short8v*)&usH[lrow * U_STR + kb];
        short8v a1h = *(const short8v*)&usH[(16 + lrow) * U_STR + kb];
        short8v b0h = *(const short8v*)(WcH + o0 * 256 + kb);
        short8v b0l = *(const short8v*)(WcL + o0 * 256 + kb);
        short8v b1h = *(const short8v*)(WcH + o1 * 256 + kb);
        short8v b1l = *(const short8v*)(WcL + o1 * 256 + kb);
        acc00 = __builtin_amdgcn_mfma_f32_16x16x32_bf16(a0h, b0h, acc00, 0, 0, 0);
        acc00 = __builtin_amdgcn_mfma_f32_16x16x32_bf16(a0h, b0l, acc00, 0, 0, 0);
        acc01 = __builtin_amdgcn_mfma_f32_16x16x32_bf16(a0h, b1h, acc01, 0, 0, 0);
        acc01 = __builtin_amdgcn_mfma_f32_16x16x32_bf16(a0h, b1l, acc01, 0, 0, 0);
        acc10 = __builtin_amdgcn_mfma_f32_16x16x32_bf16(a1h, b0h, acc10, 0, 0, 0);
        acc10 = __builtin_amdgcn_mfma_f32_16x16x32_bf16(a1h, b0l, acc10, 0, 0, 0);
        acc11 = __builtin_amdgcn_mfma_f32_16x16x32_bf16(a1h, b1h, acc11, 0, 0, 0);
        acc11 = __builtin_amdgcn_mfma_f32_16x16x32_bf16(a1h, b1l, acc11, 0, 0, 0);
    }

    // ---- bias + ReLU + split h into LDS
    {
        float bb0 = bl[wave * 32 + lrow];
        float bb1 = bl[wave * 32 + 16 + lrow];
        int c0 = wave * 32 + lrow;
        int c1 = c0 + 16;
#pragma unroll
        for (int q = 0; q < 4; ++q) {
            int r0 = qr + q;
            int r1 = 16 + qr + q;
            float v;
            v = fmaxf(acc00[q] + bb0, 0.f); splitf(v, hsH[r0 * H_STR + c0], hsL[r0 * H_STR + c0]);
            v = fmaxf(acc01[q] + bb1, 0.f); splitf(v, hsH[r0 * H_STR + c1], hsL[r0 * H_STR + c1]);
            v = fmaxf(acc10[q] + bb0, 0.f); splitf(v, hsH[r1 * H_STR + c0], hsL[r1 * H_STR + c0]);
            v = fmaxf(acc11[q] + bb1, 0.f); splitf(v, hsH[r1 * H_STR + c1], hsL[r1 * H_STR + c1]);
        }
    }
    __syncthreads();

    // ---- GEMM2: hw[32x64] = h[32x128] @ Wg^T, wave -> col-tile `wave`
    float4v acc2_0 = {0.f, 0.f, 0.f, 0.f};
    float4v acc2_1 = {0.f, 0.f, 0.f, 0.f};
    const int og = wave * 16 + lrow;
#pragma unroll
    for (int ks = 0; ks < 4; ++ks) {
        int kb = ks * 32 + lk8;
        short8v a0h = *(const short8v*)&hsH[lrow * H_STR + kb];
        short8v a0l = *(const short8v*)&hsL[lrow * H_STR + kb];
        short8v a1h = *(const short8v*)&hsH[(16 + lrow) * H_STR + kb];
        short8v a1l = *(const short8v*)&hsL[(16 + lrow) * H_STR + kb];
        short8v bh = *(const short8v*)(WgH + og * 128 + kb);
        short8v bl8 = *(const short8v*)(WgL + og * 128 + kb);
        acc2_0 = __builtin_amdgcn_mfma_f32_16x16x32_bf16(a0h, bh, acc2_0, 0, 0, 0);
        acc2_0 = __builtin_amdgcn_mfma_f32_16x16x32_bf16(a0h, bl8, acc2_0, 0, 0, 0);
        acc2_0 = __builtin_amdgcn_mfma_f32_16x16x32_bf16(a0l, bh, acc2_0, 0, 0, 0);
        acc2_1 = __builtin_amdgcn_mfma_f32_16x16x32_bf16(a1h, bh, acc2_1, 0, 0, 0);
        acc2_1 = __builtin_amdgcn_mfma_f32_16x16x32_bf16(a1h, bl8, acc2_1, 0, 0, 0);
        acc2_1 = __builtin_amdgcn_mfma_f32_16x16x32_bf16(a1l, bh, acc2_1, 0, 0, 0);
    }

    // ---- write hw dense N x 64 (f32; aliases meanL rows of this block only)
#pragma unroll
    for (int q = 0; q < 4; ++q) {
        int node0 = n0 + qr + q;
        int node1 = n0 + 16 + qr + q;
        if (node0 < N) hw[(size_t)node0 * DOUT + og] = acc2_0[q];
        if (node1 < N) hw[(size_t)node1 * DOUT + og] = acc2_1[q];
    }
}

// ---------------- gather GCN + fused softmax (one wave per node) -----------
__global__ void gather_gcn_softmax(const int* __restrict__ rowptr, const int* __restrict__ col,
                                   const float* __restrict__ hw, const float* __restrict__ dinv,
                                   const float* __restrict__ bg,
                                   float* __restrict__ out, float* __restrict__ soft, int N) {
    int node = blockIdx.x * 4 + (threadIdx.x >> 6);
    if (node >= N) return;
    int lane = threadIdx.x & 63;
    int half = lane >> 5;
    int hl = lane & 31;
    int beg = rowptr[node], end = rowptr[node + 1];
    float2 acc = make_float2(0.f, 0.f);
    int e = beg;
    for (; e + 3 < end; e += 4) {
        int sA = col[e + half];
        int sB = col[e + 2 + half];
        float wA = dinv[sA], wB = dinv[sB];
        float2 vA = *(const float2*)(hw + (size_t)sA * DOUT + hl * 2);
        float2 vB = *(const float2*)(hw + (size_t)sB * DOUT + hl * 2);
        acc.x += wA * vA.x + wB * vB.x;
        acc.y += wA * vA.y + wB * vB.y;
    }
    for (; e + 1 < end; e += 2) {
        int sA = col[e + half];
        float wA = dinv[sA];
        float2 vA = *(const float2*)(hw + (size_t)sA * DOUT + hl * 2);
        acc.x += wA * vA.x;
        acc.y += wA * vA.y;
    }
    if (e < end && half == 0) {
        int sA = col[e];
        float wA = dinv[sA];
        float2 vA = *(const float2*)(hw + (size_t)sA * DOUT + hl * 2);
        acc.x += wA * vA.x;
        acc.y += wA * vA.y;
    }
    acc.x += __shfl_xor(acc.x, 32, 64);
    acc.y += __shfl_xor(acc.y, 32, 64);

    float di = dinv[node];
    float2 selfv = *(const float2*)(hw + (size_t)node * DOUT + hl * 2);
    float v0 = di * acc.x + di * di * selfv.x + bg[hl * 2 + 0];
    float v1 = di * acc.y + di * di * selfv.y + bg[hl * 2 + 1];

    float m = fmaxf(v0, v1);
#pragma unroll
    for (int mask = 16; mask; mask >>= 1) m = fmaxf(m, __shfl_xor(m, mask, 64));
    float e0 = __expf(v0 - m), e1 = __expf(v1 - m);
    float s = e0 + e1;
#pragma unroll
    for (int mask = 16; mask; mask >>= 1) s += __shfl_xor(s, mask, 64);
    if (half == 0) {
        float2 ov = make_float2(v0, v1);
        float2 sv = make_float2(e0 / s, e1 / s);
        *(float2*)(out + (size_t)node * DOUT + hl * 2) = ov;
        *(float2*)(soft + (size_t)node * DOUT + hl * 2) = sv;
    }
}

// ---------------------------------------------------------------------------
extern "C" void kernel_launch(void* const* d_in, const int* in_sizes, int n_in,
                              void* d_out, int out_size, void* d_ws, size_t ws_size,
                              hipStream_t stream) {
    const float* x  = (const float*)d_in[0];
    const void*  ei = d_in[1];
    const float* Wl = (const float*)d_in[2];
    const float* bl = (const float*)d_in[3];
    const float* Wr = (const float*)d_in[4];
    const float* Wg = (const float*)d_in[5];
    const float* bg = (const float*)d_in[6];
    const int N = in_sizes[0] / DIN;
    const int E = in_sizes[1] / 2;
    float* out = (float*)d_out;

    char* ws = (char*)d_ws;
    size_t off = 0;
    auto alloc = [&](size_t bytes) {
        void* p = ws + off;
        off += (bytes + 255) / 256 * 256;
        return p;
    };
    int*   flag    = (int*)alloc(4);
    int*   deg     = (int*)alloc((size_t)N * 4);
    float* dinv    = (float*)alloc((size_t)N * 4);
    int*   rowptr  = (int*)alloc((size_t)(N + 1) * 4);
    int*   cursor  = (int*)alloc((size_t)N * 4);
    int*   colv    = (int*)alloc((size_t)E * 4);
    int*   partial = (int*)alloc(1024 * 4);
    unsigned short* WcH = (unsigned short*)alloc(128 * 256 * 2);
    unsigned short* WcL = (unsigned short*)alloc(128 * 256 * 2);
    unsigned short* WgH = (unsigned short*)alloc(64 * 128 * 2);
    unsigned short* WgL = (unsigned short*)alloc(64 * 128 * 2);
    unsigned short* xbf   = (unsigned short*)alloc((size_t)N * DIN * 2);
    unsigned short* meanH = (unsigned short*)alloc((size_t)N * DIN * 2);
    unsigned short* meanL = (unsigned short*)alloc((size_t)N * DIN * 2);  // also hw (f32 N*64)
    (void)ws_size; (void)n_in; (void)out_size;

    float* hw = (float*)meanL;  // byte-exact per-node alias: meanL row n (256 B)
                                // == hw row n (64 f32); safe, see sage_gemm note.
    float* soft = out + (size_t)N * DOUT;

    const int nblk = (N + 1023) / 1024;

    hipMemsetAsync(deg, 0, (size_t)N * 4, stream);

    detect_idx_kernel<<<1, 256, 0, stream>>>(ei, 2 * E, flag);
    {
        size_t xElems = (size_t)N * DIN;
        size_t total = 128 * 256 + 64 * 128 + (xElems + 3) / 4;
        prep_all<<<(int)((total + 255) / 256), 256, 0, stream>>>(
            Wl, Wr, Wg, WcH, WcL, WgH, WgL, x, xbf, xElems);
    }
    count_deg<<<(E + 255) / 256, 256, 0, stream>>>(ei, flag, deg, E);
    scan_partial<<<nblk, 256, 0, stream>>>(deg, partial, N);
    scan_offsets<<<1, 64, 0, stream>>>(partial, nblk, rowptr, N, E);
    scan_final<<<nblk, 256, 0, stream>>>(deg, partial, rowptr, cursor, dinv, N);
    fill_csr<<<(E + 255) / 256, 256, 0, stream>>>(ei, flag, cursor, colv, E);
    gather_mean<<<(N + 3) / 4, 256, 0, stream>>>(rowptr, colv, xbf, meanH, meanL, N);
    sage_gemm<<<(N + 31) / 32, 256, 0, stream>>>(meanH, meanL, xbf, WcH, WcL, WgH, WgL, bl, hw, N);
    gather_gcn_softmax<<<(N + 3) / 4, 256, 0, stream>>>(rowptr, colv, hw, dinv, bg, out, soft, N);
}

// Round 6
// 256.360 us; speedup vs baseline: 1.1329x; 1.0663x over previous
//
#include <hip/hip_runtime.h>
#include <math.h>

// GraphSAGE (mean) + GCN + softmax. Activations RNE-bf16, weights split
// hi/lo bf16 (B-side split MFMA), f32 accumulate everywhere.
// N=100000, E=625000, D_IN=D_H=128, D_OUT=64 (derived from in_sizes).

#define DIN 128
#define DH  128
#define DOUT 64
#define U_STR 264   // 256 + 8 pad (ushort): row 528B, 16B-aligned
#define H_STR 136   // 128 + 8 pad (ushort): row 272B, 16B-aligned

typedef __attribute__((ext_vector_type(8))) short short8v;            // 8 bf16
typedef __attribute__((ext_vector_type(4))) float float4v;            // MFMA acc
typedef __attribute__((ext_vector_type(4))) unsigned short ushort4v;  // 4 bf16
typedef __attribute__((ext_vector_type(2))) unsigned short ushort2v;  // 2 bf16

// split f32 -> bf16 hi (truncate) + bf16 lo (residual, truncate)
__device__ __forceinline__ void splitf(float a, unsigned short& hi, unsigned short& lo) {
    unsigned ai = __float_as_uint(a);
    hi = (unsigned short)(ai >> 16);
    float r = a - __uint_as_float(ai & 0xffff0000u);
    lo = (unsigned short)(__float_as_uint(r) >> 16);
}

// f32 -> bf16 round-to-nearest-even
__device__ __forceinline__ unsigned short f2bf_rne(float f) {
    unsigned u = __float_as_uint(f);
    return (unsigned short)((u + 0x7fffu + ((u >> 16) & 1u)) >> 16);
}

__device__ __forceinline__ float bf2f(unsigned short u) {
    return __uint_as_float(((unsigned)u) << 16);
}

// ---------------- edge-index dtype detection (int64 vs int32) --------------
__global__ void detect_idx_kernel(const void* ei, int twoE, int* flag) {
    __shared__ int ok;
    if (threadIdx.x == 0) ok = 1;
    __syncthreads();
    const int* p = (const int*)ei;
    for (int i = threadIdx.x; i < 512; i += blockDim.x) {
        long long pos = 1 + ((long long)i * (long long)(twoE - 2)) / 512;
        pos |= 1;
        if (pos < twoE && p[pos] != 0) ok = 0;
    }
    __syncthreads();
    if (threadIdx.x == 0) *flag = ok;  // 1 => int64, 0 => int32
}

__device__ __forceinline__ void load_edge(const void* ei, int e, int E, int is64,
                                          int& s, int& d) {
    if (is64) {
        const long long* p = (const long long*)ei;
        s = (int)p[e];
        d = (int)p[E + e];
    } else {
        const int* p = (const int*)ei;
        s = p[e];
        d = p[E + e];
    }
}

// ---------------- prep: weight split + x -> bf16 ---------------------------
__global__ void prep_all(const float* __restrict__ Wl, const float* __restrict__ Wr,
                         const float* __restrict__ Wg,
                         unsigned short* __restrict__ WcH, unsigned short* __restrict__ WcL,
                         unsigned short* __restrict__ WgH, unsigned short* __restrict__ WgL,
                         const float* __restrict__ x, unsigned short* __restrict__ xbf,
                         size_t xElems) {
    size_t idx = (size_t)blockIdx.x * 256 + threadIdx.x;
    if (idx < 128 * 256) {
        int o = (int)(idx >> 8), k = (int)(idx & 255);
        float v = (k < 128) ? Wl[o * 128 + k] : Wr[o * 128 + (k - 128)];
        unsigned short h, l;
        splitf(v, h, l);
        WcH[idx] = h; WcL[idx] = l;
    } else if (idx < 128 * 256 + 64 * 128) {
        size_t j = idx - 128 * 256;
        unsigned short h, l;
        splitf(Wg[j], h, l);
        WgH[j] = h; WgL[j] = l;
    } else {
        size_t j = (idx - (128 * 256 + 64 * 128)) * 4;
        if (j < xElems) {
            float4 v = *(const float4*)(x + j);
            ushort4v o;
            o[0] = f2bf_rne(v.x);
            o[1] = f2bf_rne(v.y);
            o[2] = f2bf_rne(v.z);
            o[3] = f2bf_rne(v.w);
            *(ushort4v*)(xbf + j) = o;
        }
    }
}

// ---------------- CSR build -----------------------------------------------
__global__ void count_deg(const void* __restrict__ ei, const int* __restrict__ flag,
                          int* __restrict__ deg, int E) {
    int e = blockIdx.x * 256 + threadIdx.x;
    if (e >= E) return;
    int s, d;
    load_edge(ei, e, E, *flag, s, d);
    atomicAdd(&deg[d], 1);
}

__global__ void scan_partial(const int* __restrict__ deg, int* __restrict__ partial, int N) {
    int base = blockIdx.x * 1024;
    int t = threadIdx.x;
    int s = 0;
    for (int i = t; i < 1024; i += 256) {
        int g = base + i;
        if (g < N) s += deg[g];
    }
    __shared__ int sh[256];
    sh[t] = s;
    __syncthreads();
    for (int off = 128; off; off >>= 1) {
        if (t < off) sh[t] += sh[t + off];
        __syncthreads();
    }
    if (t == 0) partial[blockIdx.x] = sh[0];
}

__global__ void scan_offsets(int* partial, int nblk, int* rowptr, int N, int E) {
    if (threadIdx.x == 0 && blockIdx.x == 0) {
        int run = 0;
        for (int i = 0; i < nblk; ++i) {
            int v = partial[i];
            partial[i] = run;
            run += v;
        }
        rowptr[N] = E;
    }
}

__global__ void scan_final(const int* __restrict__ deg, const int* __restrict__ partial,
                           int* __restrict__ rowptr, int* __restrict__ cursor,
                           float* __restrict__ dinv, int N) {
    int base = blockIdx.x * 1024;
    int t = threadIdx.x;
    int i0 = base + t * 4;
    int v[4];
    int s = 0;
#pragma unroll
    for (int j = 0; j < 4; ++j) {
        int g = i0 + j;
        v[j] = (g < N) ? deg[g] : 0;
        s += v[j];
    }
    __shared__ int sh[256];
    sh[t] = s;
    __syncthreads();
    for (int off = 1; off < 256; off <<= 1) {
        int val = (t >= off) ? sh[t - off] : 0;
        __syncthreads();
        sh[t] += val;
        __syncthreads();
    }
    int pre = sh[t] - s + partial[blockIdx.x];
#pragma unroll
    for (int j = 0; j < 4; ++j) {
        int g = i0 + j;
        if (g < N) {
            rowptr[g] = pre;
            cursor[g] = pre;
            dinv[g] = rsqrtf((float)v[j] + 1.0f);
            pre += v[j];
        }
    }
}

__global__ void fill_csr(const void* __restrict__ ei, const int* __restrict__ flag,
                         int* __restrict__ cursor, int* __restrict__ col, int E) {
    int e = blockIdx.x * 256 + threadIdx.x;
    if (e >= E) return;
    int s, d;
    load_edge(ei, e, E, *flag, s, d);
    int pos = atomicAdd(&cursor[d], 1);
    col[pos] = s;
}

// ---------------- gather mean from bf16 x (one wave per node) --------------
__global__ void gather_mean(const int* __restrict__ rowptr, const int* __restrict__ col,
                            const unsigned short* __restrict__ xbf,
                            unsigned short* __restrict__ meanbf, int N) {
    int node = blockIdx.x * 4 + (threadIdx.x >> 6);
    if (node >= N) return;
    int lane = threadIdx.x & 63;
    int half = lane >> 5;
    int hl = lane & 31;
    int beg = rowptr[node], end = rowptr[node + 1];
    float a0 = 0.f, a1 = 0.f, a2 = 0.f, a3 = 0.f;
    int e = beg;
    for (; e + 3 < end; e += 4) {
        int sA = col[e + half];
        int sB = col[e + 2 + half];
        ushort4v vA = *(const ushort4v*)(xbf + (size_t)sA * DIN + hl * 4);
        ushort4v vB = *(const ushort4v*)(xbf + (size_t)sB * DIN + hl * 4);
        a0 += bf2f(vA[0]) + bf2f(vB[0]);
        a1 += bf2f(vA[1]) + bf2f(vB[1]);
        a2 += bf2f(vA[2]) + bf2f(vB[2]);
        a3 += bf2f(vA[3]) + bf2f(vB[3]);
    }
    for (; e + 1 < end; e += 2) {
        int sA = col[e + half];
        ushort4v vA = *(const ushort4v*)(xbf + (size_t)sA * DIN + hl * 4);
        a0 += bf2f(vA[0]);
        a1 += bf2f(vA[1]);
        a2 += bf2f(vA[2]);
        a3 += bf2f(vA[3]);
    }
    if (e < end && half == 0) {
        int sA = col[e];
        ushort4v vA = *(const ushort4v*)(xbf + (size_t)sA * DIN + hl * 4);
        a0 += bf2f(vA[0]);
        a1 += bf2f(vA[1]);
        a2 += bf2f(vA[2]);
        a3 += bf2f(vA[3]);
    }
    a0 += __shfl_xor(a0, 32, 64);
    a1 += __shfl_xor(a1, 32, 64);
    a2 += __shfl_xor(a2, 32, 64);
    a3 += __shfl_xor(a3, 32, 64);
    if (half == 0) {
        float invd = (end > beg) ? 1.0f / (float)(end - beg) : 0.f;
        ushort4v H;
        H[0] = f2bf_rne(a0 * invd);
        H[1] = f2bf_rne(a1 * invd);
        H[2] = f2bf_rne(a2 * invd);
        H[3] = f2bf_rne(a3 * invd);
        *(ushort4v*)(meanbf + (size_t)node * DIN + hl * 4) = H;
    }
}

// ---------------- GEMM: h = relu([mean|x]@Wcat^T + bl); hw = h@Wg^T --------
// 32 nodes/block, 256 threads (4 waves). A-side = RNE bf16 (no split);
// B-side split hi/lo. LDS 25.6 KB -> ~6 blocks/CU.
__global__ __launch_bounds__(256) void sage_gemm(
    const unsigned short* __restrict__ meanbf,
    const unsigned short* __restrict__ xbf,
    const unsigned short* __restrict__ WcH, const unsigned short* __restrict__ WcL,
    const unsigned short* __restrict__ WgH, const unsigned short* __restrict__ WgL,
    const float* __restrict__ bl, unsigned short* __restrict__ hwbf, int N)
{
    __shared__ unsigned short usH[32 * U_STR];
    __shared__ unsigned short hsH[32 * H_STR];
    const int tid = threadIdx.x;
    const int n0 = blockIdx.x * 32;

    // ---- stage A-side: usH = [meanbf | xbf], 16B loads
    for (int idx = tid; idx < 32 * 32; idx += 256) {
        int n = idx >> 5;
        int c8 = (idx & 31) << 3;
        int node = n0 + n;
        if (node >= N) node = N - 1;
        short8v v = (c8 < 128)
                        ? *(const short8v*)(meanbf + (size_t)node * DIN + c8)
                        : *(const short8v*)(xbf + (size_t)node * DIN + (c8 - 128));
        *(short8v*)(usH + n * U_STR + c8) = v;
    }
    __syncthreads();

    const int wave = tid >> 6;
    const int lane = tid & 63;
    const int lrow = lane & 15;        // A-row / B-out / D-col
    const int lk8  = (lane >> 4) << 3; // k base within K=32 step
    const int qr   = (lane >> 4) << 2; // D-row base

    float4v acc00 = {0.f, 0.f, 0.f, 0.f};
    float4v acc01 = {0.f, 0.f, 0.f, 0.f};
    float4v acc10 = {0.f, 0.f, 0.f, 0.f};
    float4v acc11 = {0.f, 0.f, 0.f, 0.f};
    const int o0 = wave * 32 + lrow;
    const int o1 = o0 + 16;

    // ---- GEMM1: 2 MFMA per acc per ks (A plain, B hi+lo)
#pragma unroll
    for (int ks = 0; ks < 8; ++ks) {
        int kb = ks * 32 + lk8;
        short8v a0 = *(const short8v*)&usH[lrow * U_STR + kb];
        short8v a1 = *(const short8v*)&usH[(16 + lrow) * U_STR + kb];
        short8v b0h = *(const short8v*)(WcH + o0 * 256 + kb);
        short8v b0l = *(const short8v*)(WcL + o0 * 256 + kb);
        short8v b1h = *(const short8v*)(WcH + o1 * 256 + kb);
        short8v b1l = *(const short8v*)(WcL + o1 * 256 + kb);
        acc00 = __builtin_amdgcn_mfma_f32_16x16x32_bf16(a0, b0h, acc00, 0, 0, 0);
        acc00 = __builtin_amdgcn_mfma_f32_16x16x32_bf16(a0, b0l, acc00, 0, 0, 0);
        acc01 = __builtin_amdgcn_mfma_f32_16x16x32_bf16(a0, b1h, acc01, 0, 0, 0);
        acc01 = __builtin_amdgcn_mfma_f32_16x16x32_bf16(a0, b1l, acc01, 0, 0, 0);
        acc10 = __builtin_amdgcn_mfma_f32_16x16x32_bf16(a1, b0h, acc10, 0, 0, 0);
        acc10 = __builtin_amdgcn_mfma_f32_16x16x32_bf16(a1, b0l, acc10, 0, 0, 0);
        acc11 = __builtin_amdgcn_mfma_f32_16x16x32_bf16(a1, b1h, acc11, 0, 0, 0);
        acc11 = __builtin_amdgcn_mfma_f32_16x16x32_bf16(a1, b1l, acc11, 0, 0, 0);
    }

    // ---- bias + ReLU -> RNE bf16 h into LDS
    {
        float bb0 = bl[wave * 32 + lrow];
        float bb1 = bl[wave * 32 + 16 + lrow];
        int c0 = wave * 32 + lrow;
        int c1 = c0 + 16;
#pragma unroll
        for (int q = 0; q < 4; ++q) {
            int r0 = qr + q;
            int r1 = 16 + qr + q;
            hsH[r0 * H_STR + c0] = f2bf_rne(fmaxf(acc00[q] + bb0, 0.f));
            hsH[r0 * H_STR + c1] = f2bf_rne(fmaxf(acc01[q] + bb1, 0.f));
            hsH[r1 * H_STR + c0] = f2bf_rne(fmaxf(acc10[q] + bb0, 0.f));
            hsH[r1 * H_STR + c1] = f2bf_rne(fmaxf(acc11[q] + bb1, 0.f));
        }
    }
    __syncthreads();

    // ---- GEMM2: hw[32x64] = h[32x128] @ Wg^T, wave -> col-tile `wave`
    float4v acc2_0 = {0.f, 0.f, 0.f, 0.f};
    float4v acc2_1 = {0.f, 0.f, 0.f, 0.f};
    const int og = wave * 16 + lrow;
#pragma unroll
    for (int ks = 0; ks < 4; ++ks) {
        int kb = ks * 32 + lk8;
        short8v a0 = *(const short8v*)&hsH[lrow * H_STR + kb];
        short8v a1 = *(const short8v*)&hsH[(16 + lrow) * H_STR + kb];
        short8v bh = *(const short8v*)(WgH + og * 128 + kb);
        short8v bl8 = *(const short8v*)(WgL + og * 128 + kb);
        acc2_0 = __builtin_amdgcn_mfma_f32_16x16x32_bf16(a0, bh, acc2_0, 0, 0, 0);
        acc2_0 = __builtin_amdgcn_mfma_f32_16x16x32_bf16(a0, bl8, acc2_0, 0, 0, 0);
        acc2_1 = __builtin_amdgcn_mfma_f32_16x16x32_bf16(a1, bh, acc2_1, 0, 0, 0);
        acc2_1 = __builtin_amdgcn_mfma_f32_16x16x32_bf16(a1, bl8, acc2_1, 0, 0, 0);
    }

    // ---- write hw as RNE bf16, dense N x 64
#pragma unroll
    for (int q = 0; q < 4; ++q) {
        int node0 = n0 + qr + q;
        int node1 = n0 + 16 + qr + q;
        if (node0 < N) hwbf[(size_t)node0 * DOUT + og] = f2bf_rne(acc2_0[q]);
        if (node1 < N) hwbf[(size_t)node1 * DOUT + og] = f2bf_rne(acc2_1[q]);
    }
}

// ---------------- gather GCN + fused softmax (one wave per node) -----------
// hw rows are bf16 (128 B): half-wave per neighbor, ushort2/lane.
__global__ void gather_gcn_softmax(const int* __restrict__ rowptr, const int* __restrict__ col,
                                   const unsigned short* __restrict__ hwbf,
                                   const float* __restrict__ dinv,
                                   const float* __restrict__ bg,
                                   float* __restrict__ out, float* __restrict__ soft, int N) {
    int node = blockIdx.x * 4 + (threadIdx.x >> 6);
    if (node >= N) return;
    int lane = threadIdx.x & 63;
    int half = lane >> 5;
    int hl = lane & 31;
    int beg = rowptr[node], end = rowptr[node + 1];
    float accx = 0.f, accy = 0.f;
    int e = beg;
    for (; e + 3 < end; e += 4) {
        int sA = col[e + half];
        int sB = col[e + 2 + half];
        float wA = dinv[sA], wB = dinv[sB];
        ushort2v vA = *(const ushort2v*)(hwbf + (size_t)sA * DOUT + hl * 2);
        ushort2v vB = *(const ushort2v*)(hwbf + (size_t)sB * DOUT + hl * 2);
        accx += wA * bf2f(vA[0]) + wB * bf2f(vB[0]);
        accy += wA * bf2f(vA[1]) + wB * bf2f(vB[1]);
    }
    for (; e + 1 < end; e += 2) {
        int sA = col[e + half];
        float wA = dinv[sA];
        ushort2v vA = *(const ushort2v*)(hwbf + (size_t)sA * DOUT + hl * 2);
        accx += wA * bf2f(vA[0]);
        accy += wA * bf2f(vA[1]);
    }
    if (e < end && half == 0) {
        int sA = col[e];
        float wA = dinv[sA];
        ushort2v vA = *(const ushort2v*)(hwbf + (size_t)sA * DOUT + hl * 2);
        accx += wA * bf2f(vA[0]);
        accy += wA * bf2f(vA[1]);
    }
    accx += __shfl_xor(accx, 32, 64);
    accy += __shfl_xor(accy, 32, 64);

    float di = dinv[node];
    ushort2v selfv = *(const ushort2v*)(hwbf + (size_t)node * DOUT + hl * 2);
    float v0 = di * accx + di * di * bf2f(selfv[0]) + bg[hl * 2 + 0];
    float v1 = di * accy + di * di * bf2f(selfv[1]) + bg[hl * 2 + 1];

    float m = fmaxf(v0, v1);
#pragma unroll
    for (int mask = 16; mask; mask >>= 1) m = fmaxf(m, __shfl_xor(m, mask, 64));
    float e0 = __expf(v0 - m), e1 = __expf(v1 - m);
    float s = e0 + e1;
#pragma unroll
    for (int mask = 16; mask; mask >>= 1) s += __shfl_xor(s, mask, 64);
    if (half == 0) {
        float2 ov = make_float2(v0, v1);
        float2 sv = make_float2(e0 / s, e1 / s);
        *(float2*)(out + (size_t)node * DOUT + hl * 2) = ov;
        *(float2*)(soft + (size_t)node * DOUT + hl * 2) = sv;
    }
}

// ---------------------------------------------------------------------------
extern "C" void kernel_launch(void* const* d_in, const int* in_sizes, int n_in,
                              void* d_out, int out_size, void* d_ws, size_t ws_size,
                              hipStream_t stream) {
    const float* x  = (const float*)d_in[0];
    const void*  ei = d_in[1];
    const float* Wl = (const float*)d_in[2];
    const float* bl = (const float*)d_in[3];
    const float* Wr = (const float*)d_in[4];
    const float* Wg = (const float*)d_in[5];
    const float* bg = (const float*)d_in[6];
    const int N = in_sizes[0] / DIN;
    const int E = in_sizes[1] / 2;
    float* out = (float*)d_out;

    char* ws = (char*)d_ws;
    size_t off = 0;
    auto alloc = [&](size_t bytes) {
        void* p = ws + off;
        off += (bytes + 255) / 256 * 256;
        return p;
    };
    int*   flag    = (int*)alloc(4);
    int*   deg     = (int*)alloc((size_t)N * 4);
    float* dinv    = (float*)alloc((size_t)N * 4);
    int*   rowptr  = (int*)alloc((size_t)(N + 1) * 4);
    int*   cursor  = (int*)alloc((size_t)N * 4);
    int*   colv    = (int*)alloc((size_t)E * 4);
    int*   partial = (int*)alloc(1024 * 4);
    unsigned short* WcH = (unsigned short*)alloc(128 * 256 * 2);
    unsigned short* WcL = (unsigned short*)alloc(128 * 256 * 2);
    unsigned short* WgH = (unsigned short*)alloc(64 * 128 * 2);
    unsigned short* WgL = (unsigned short*)alloc(64 * 128 * 2);
    unsigned short* xbf    = (unsigned short*)alloc((size_t)N * DIN * 2);
    unsigned short* meanbf = (unsigned short*)alloc((size_t)N * DIN * 2);
    unsigned short* hwbf   = (unsigned short*)alloc((size_t)N * DOUT * 2);
    (void)ws_size; (void)n_in; (void)out_size;

    float* soft = out + (size_t)N * DOUT;

    const int nblk = (N + 1023) / 1024;

    hipMemsetAsync(deg, 0, (size_t)N * 4, stream);

    detect_idx_kernel<<<1, 256, 0, stream>>>(ei, 2 * E, flag);
    {
        size_t xElems = (size_t)N * DIN;
        size_t total = 128 * 256 + 64 * 128 + (xElems + 3) / 4;
        prep_all<<<(int)((total + 255) / 256), 256, 0, stream>>>(
            Wl, Wr, Wg, WcH, WcL, WgH, WgL, x, xbf, xElems);
    }
    count_deg<<<(E + 255) / 256, 256, 0, stream>>>(ei, flag, deg, E);
    scan_partial<<<nblk, 256, 0, stream>>>(deg, partial, N);
    scan_offsets<<<1, 64, 0, stream>>>(partial, nblk, rowptr, N, E);
    scan_final<<<nblk, 256, 0, stream>>>(deg, partial, rowptr, cursor, dinv, N);
    fill_csr<<<(E + 255) / 256, 256, 0, stream>>>(ei, flag, cursor, colv, E);
    gather_mean<<<(N + 3) / 4, 256, 0, stream>>>(rowptr, colv, xbf, meanbf, N);
    sage_gemm<<<(N + 31) / 32, 256, 0, stream>>>(meanbf, xbf, WcH, WcL, WgH, WgL, bl, hwbf, N);
    gather_gcn_softmax<<<(N + 3) / 4, 256, 0, stream>>>(rowptr, colv, hwbf, dinv, bg, out, soft, N);
}

// Round 7
// 235.368 us; speedup vs baseline: 1.2340x; 1.0892x over previous
//
#include <hip/hip_runtime.h>
#include <math.h>

// GraphSAGE (mean) + GCN + softmax. Activations RNE-bf16, weights split
// hi/lo bf16 (B-side split MFMA), f32 accumulate everywhere.
// sage_gemm: B prefetched to registers, 2 node-tiles/block, A double-buffered.
// N=100000, E=625000, D_IN=D_H=128, D_OUT=64 (derived from in_sizes).

#define DIN 128
#define DH  128
#define DOUT 64
#define U_STR 264   // 256 + 8 pad (ushort): row 528B, 16B-aligned
#define H_STR 136   // 128 + 8 pad (ushort): row 272B, 16B-aligned

typedef __attribute__((ext_vector_type(8))) short short8v;            // 8 bf16
typedef __attribute__((ext_vector_type(4))) float float4v;            // MFMA acc
typedef __attribute__((ext_vector_type(4))) unsigned short ushort4v;  // 4 bf16
typedef __attribute__((ext_vector_type(2))) unsigned short ushort2v;  // 2 bf16

// split f32 -> bf16 hi (truncate) + bf16 lo (residual, truncate)
__device__ __forceinline__ void splitf(float a, unsigned short& hi, unsigned short& lo) {
    unsigned ai = __float_as_uint(a);
    hi = (unsigned short)(ai >> 16);
    float r = a - __uint_as_float(ai & 0xffff0000u);
    lo = (unsigned short)(__float_as_uint(r) >> 16);
}

// f32 -> bf16 round-to-nearest-even
__device__ __forceinline__ unsigned short f2bf_rne(float f) {
    unsigned u = __float_as_uint(f);
    return (unsigned short)((u + 0x7fffu + ((u >> 16) & 1u)) >> 16);
}

__device__ __forceinline__ float bf2f(unsigned short u) {
    return __uint_as_float(((unsigned)u) << 16);
}

// ---------------- edge-index dtype detection (int64 vs int32) --------------
__global__ void detect_idx_kernel(const void* ei, int twoE, int* flag) {
    __shared__ int ok;
    if (threadIdx.x == 0) ok = 1;
    __syncthreads();
    const int* p = (const int*)ei;
    for (int i = threadIdx.x; i < 512; i += blockDim.x) {
        long long pos = 1 + ((long long)i * (long long)(twoE - 2)) / 512;
        pos |= 1;
        if (pos < twoE && p[pos] != 0) ok = 0;
    }
    __syncthreads();
    if (threadIdx.x == 0) *flag = ok;  // 1 => int64, 0 => int32
}

__device__ __forceinline__ void load_edge(const void* ei, int e, int E, int is64,
                                          int& s, int& d) {
    if (is64) {
        const long long* p = (const long long*)ei;
        s = (int)p[e];
        d = (int)p[E + e];
    } else {
        const int* p = (const int*)ei;
        s = p[e];
        d = p[E + e];
    }
}

// ---------------- prep: weight split + x -> bf16 ---------------------------
__global__ void prep_all(const float* __restrict__ Wl, const float* __restrict__ Wr,
                         const float* __restrict__ Wg,
                         unsigned short* __restrict__ WcH, unsigned short* __restrict__ WcL,
                         unsigned short* __restrict__ WgH, unsigned short* __restrict__ WgL,
                         const float* __restrict__ x, unsigned short* __restrict__ xbf,
                         size_t xElems) {
    size_t idx = (size_t)blockIdx.x * 256 + threadIdx.x;
    if (idx < 128 * 256) {
        int o = (int)(idx >> 8), k = (int)(idx & 255);
        float v = (k < 128) ? Wl[o * 128 + k] : Wr[o * 128 + (k - 128)];
        unsigned short h, l;
        splitf(v, h, l);
        WcH[idx] = h; WcL[idx] = l;
    } else if (idx < 128 * 256 + 64 * 128) {
        size_t j = idx - 128 * 256;
        unsigned short h, l;
        splitf(Wg[j], h, l);
        WgH[j] = h; WgL[j] = l;
    } else {
        size_t j = (idx - (128 * 256 + 64 * 128)) * 4;
        if (j < xElems) {
            float4 v = *(const float4*)(x + j);
            ushort4v o;
            o[0] = f2bf_rne(v.x);
            o[1] = f2bf_rne(v.y);
            o[2] = f2bf_rne(v.z);
            o[3] = f2bf_rne(v.w);
            *(ushort4v*)(xbf + j) = o;
        }
    }
}

// ---------------- CSR build -----------------------------------------------
__global__ void count_deg(const void* __restrict__ ei, const int* __restrict__ flag,
                          int* __restrict__ deg, int E) {
    int e = blockIdx.x * 256 + threadIdx.x;
    if (e >= E) return;
    int s, d;
    load_edge(ei, e, E, *flag, s, d);
    atomicAdd(&deg[d], 1);
}

__global__ void scan_partial(const int* __restrict__ deg, int* __restrict__ partial, int N) {
    int base = blockIdx.x * 1024;
    int t = threadIdx.x;
    int s = 0;
    for (int i = t; i < 1024; i += 256) {
        int g = base + i;
        if (g < N) s += deg[g];
    }
    __shared__ int sh[256];
    sh[t] = s;
    __syncthreads();
    for (int off = 128; off; off >>= 1) {
        if (t < off) sh[t] += sh[t + off];
        __syncthreads();
    }
    if (t == 0) partial[blockIdx.x] = sh[0];
}

__global__ void scan_offsets(int* partial, int nblk, int* rowptr, int N, int E) {
    if (threadIdx.x == 0 && blockIdx.x == 0) {
        int run = 0;
        for (int i = 0; i < nblk; ++i) {
            int v = partial[i];
            partial[i] = run;
            run += v;
        }
        rowptr[N] = E;
    }
}

__global__ void scan_final(const int* __restrict__ deg, const int* __restrict__ partial,
                           int* __restrict__ rowptr, int* __restrict__ cursor,
                           float* __restrict__ dinv, int N) {
    int base = blockIdx.x * 1024;
    int t = threadIdx.x;
    int i0 = base + t * 4;
    int v[4];
    int s = 0;
#pragma unroll
    for (int j = 0; j < 4; ++j) {
        int g = i0 + j;
        v[j] = (g < N) ? deg[g] : 0;
        s += v[j];
    }
    __shared__ int sh[256];
    sh[t] = s;
    __syncthreads();
    for (int off = 1; off < 256; off <<= 1) {
        int val = (t >= off) ? sh[t - off] : 0;
        __syncthreads();
        sh[t] += val;
        __syncthreads();
    }
    int pre = sh[t] - s + partial[blockIdx.x];
#pragma unroll
    for (int j = 0; j < 4; ++j) {
        int g = i0 + j;
        if (g < N) {
            rowptr[g] = pre;
            cursor[g] = pre;
            dinv[g] = rsqrtf((float)v[j] + 1.0f);
            pre += v[j];
        }
    }
}

__global__ void fill_csr(const void* __restrict__ ei, const int* __restrict__ flag,
                         int* __restrict__ cursor, int* __restrict__ col, int E) {
    int e = blockIdx.x * 256 + threadIdx.x;
    if (e >= E) return;
    int s, d;
    load_edge(ei, e, E, *flag, s, d);
    int pos = atomicAdd(&cursor[d], 1);
    col[pos] = s;
}

// ---------------- gather mean from bf16 x (one wave per node) --------------
__global__ void gather_mean(const int* __restrict__ rowptr, const int* __restrict__ col,
                            const unsigned short* __restrict__ xbf,
                            unsigned short* __restrict__ meanbf, int N) {
    int node = blockIdx.x * 4 + (threadIdx.x >> 6);
    if (node >= N) return;
    int lane = threadIdx.x & 63;
    int half = lane >> 5;
    int hl = lane & 31;
    int beg = rowptr[node], end = rowptr[node + 1];
    float a0 = 0.f, a1 = 0.f, a2 = 0.f, a3 = 0.f;
    int e = beg;
    for (; e + 7 < end; e += 8) {   // 4 rows in flight per half-wave
        int s0 = col[e + half];
        int s1 = col[e + 2 + half];
        int s2 = col[e + 4 + half];
        int s3 = col[e + 6 + half];
        ushort4v v0 = *(const ushort4v*)(xbf + (size_t)s0 * DIN + hl * 4);
        ushort4v v1 = *(const ushort4v*)(xbf + (size_t)s1 * DIN + hl * 4);
        ushort4v v2 = *(const ushort4v*)(xbf + (size_t)s2 * DIN + hl * 4);
        ushort4v v3 = *(const ushort4v*)(xbf + (size_t)s3 * DIN + hl * 4);
        a0 += bf2f(v0[0]) + bf2f(v1[0]) + bf2f(v2[0]) + bf2f(v3[0]);
        a1 += bf2f(v0[1]) + bf2f(v1[1]) + bf2f(v2[1]) + bf2f(v3[1]);
        a2 += bf2f(v0[2]) + bf2f(v1[2]) + bf2f(v2[2]) + bf2f(v3[2]);
        a3 += bf2f(v0[3]) + bf2f(v1[3]) + bf2f(v2[3]) + bf2f(v3[3]);
    }
    for (; e + 3 < end; e += 4) {
        int s0 = col[e + half];
        int s1 = col[e + 2 + half];
        ushort4v v0 = *(const ushort4v*)(xbf + (size_t)s0 * DIN + hl * 4);
        ushort4v v1 = *(const ushort4v*)(xbf + (size_t)s1 * DIN + hl * 4);
        a0 += bf2f(v0[0]) + bf2f(v1[0]);
        a1 += bf2f(v0[1]) + bf2f(v1[1]);
        a2 += bf2f(v0[2]) + bf2f(v1[2]);
        a3 += bf2f(v0[3]) + bf2f(v1[3]);
    }
    for (; e + 1 < end; e += 2) {
        int s0 = col[e + half];
        ushort4v v0 = *(const ushort4v*)(xbf + (size_t)s0 * DIN + hl * 4);
        a0 += bf2f(v0[0]);
        a1 += bf2f(v0[1]);
        a2 += bf2f(v0[2]);
        a3 += bf2f(v0[3]);
    }
    if (e < end && half == 0) {
        int s0 = col[e];
        ushort4v v0 = *(const ushort4v*)(xbf + (size_t)s0 * DIN + hl * 4);
        a0 += bf2f(v0[0]);
        a1 += bf2f(v0[1]);
        a2 += bf2f(v0[2]);
        a3 += bf2f(v0[3]);
    }
    a0 += __shfl_xor(a0, 32, 64);
    a1 += __shfl_xor(a1, 32, 64);
    a2 += __shfl_xor(a2, 32, 64);
    a3 += __shfl_xor(a3, 32, 64);
    if (half == 0) {
        float invd = (end > beg) ? 1.0f / (float)(end - beg) : 0.f;
        ushort4v H;
        H[0] = f2bf_rne(a0 * invd);
        H[1] = f2bf_rne(a1 * invd);
        H[2] = f2bf_rne(a2 * invd);
        H[3] = f2bf_rne(a3 * invd);
        *(ushort4v*)(meanbf + (size_t)node * DIN + hl * 4) = H;
    }
}

// ---------------- GEMM: h = relu([mean|x]@Wcat^T + bl); hw = h@Wg^T --------
// 64 nodes/block (2 tiles), 256 threads (4 waves). B prefetched to registers
// once per block; A double-buffered in LDS.
__global__ __launch_bounds__(256) void sage_gemm(
    const unsigned short* __restrict__ meanbf,
    const unsigned short* __restrict__ xbf,
    const unsigned short* __restrict__ WcH, const unsigned short* __restrict__ WcL,
    const unsigned short* __restrict__ WgH, const unsigned short* __restrict__ WgL,
    const float* __restrict__ bl, unsigned short* __restrict__ hwbf, int N)
{
    __shared__ unsigned short usH[2][32 * U_STR];
    __shared__ unsigned short hsH[32 * H_STR];
    const int tid = threadIdx.x;
    const int wave = tid >> 6;
    const int lane = tid & 63;
    const int lrow = lane & 15;        // A-row / B-out / D-col
    const int lk8  = (lane >> 4) << 3; // k base within K=32 step
    const int qr   = (lane >> 4) << 2; // D-row base
    const int n0 = blockIdx.x * 64;

    // ---- prefetch ALL B fragments to registers (one latency batch)
    const int o0 = wave * 32 + lrow;
    const int o1 = o0 + 16;
    short8v B1[8][4];   // [ks][b0h,b0l,b1h,b1l]
#pragma unroll
    for (int ks = 0; ks < 8; ++ks) {
        int kb = ks * 32 + lk8;
        B1[ks][0] = *(const short8v*)(WcH + o0 * 256 + kb);
        B1[ks][1] = *(const short8v*)(WcL + o0 * 256 + kb);
        B1[ks][2] = *(const short8v*)(WcH + o1 * 256 + kb);
        B1[ks][3] = *(const short8v*)(WcL + o1 * 256 + kb);
    }
    const int og = wave * 16 + lrow;
    short8v B2[4][2];   // [ks][h,l]
#pragma unroll
    for (int ks = 0; ks < 4; ++ks) {
        int kb = ks * 32 + lk8;
        B2[ks][0] = *(const short8v*)(WgH + og * 128 + kb);
        B2[ks][1] = *(const short8v*)(WgL + og * 128 + kb);
    }
    const float bb0 = bl[o0];
    const float bb1 = bl[o1];

    // ---- cooperative A staging into buf
    auto stage = [&](int buf, int nb) {
        for (int idx = tid; idx < 32 * 32; idx += 256) {
            int n = idx >> 5;
            int c8 = (idx & 31) << 3;
            int node = nb + n;
            if (node >= N) node = N - 1;
            short8v v = (c8 < 128)
                            ? *(const short8v*)(meanbf + (size_t)node * DIN + c8)
                            : *(const short8v*)(xbf + (size_t)node * DIN + (c8 - 128));
            *(short8v*)(&usH[buf][n * U_STR + c8]) = v;
        }
    };

    stage(0, n0);
    __syncthreads();

#pragma unroll
    for (int t = 0; t < 2; ++t) {
        if (t == 0) stage(1, n0 + 32);   // overlap with tile-0 MFMAs

        const int nb = n0 + t * 32;
        float4v acc00 = {0.f, 0.f, 0.f, 0.f};
        float4v acc01 = {0.f, 0.f, 0.f, 0.f};
        float4v acc10 = {0.f, 0.f, 0.f, 0.f};
        float4v acc11 = {0.f, 0.f, 0.f, 0.f};

        // ---- GEMM1: 8 MFMA per ks (A plain, B hi+lo, 2 node-sub x 2 out-sub)
#pragma unroll
        for (int ks = 0; ks < 8; ++ks) {
            int kb = ks * 32 + lk8;
            short8v a0 = *(const short8v*)&usH[t][lrow * U_STR + kb];
            short8v a1 = *(const short8v*)&usH[t][(16 + lrow) * U_STR + kb];
            acc00 = __builtin_amdgcn_mfma_f32_16x16x32_bf16(a0, B1[ks][0], acc00, 0, 0, 0);
            acc00 = __builtin_amdgcn_mfma_f32_16x16x32_bf16(a0, B1[ks][1], acc00, 0, 0, 0);
            acc01 = __builtin_amdgcn_mfma_f32_16x16x32_bf16(a0, B1[ks][2], acc01, 0, 0, 0);
            acc01 = __builtin_amdgcn_mfma_f32_16x16x32_bf16(a0, B1[ks][3], acc01, 0, 0, 0);
            acc10 = __builtin_amdgcn_mfma_f32_16x16x32_bf16(a1, B1[ks][0], acc10, 0, 0, 0);
            acc10 = __builtin_amdgcn_mfma_f32_16x16x32_bf16(a1, B1[ks][1], acc10, 0, 0, 0);
            acc11 = __builtin_amdgcn_mfma_f32_16x16x32_bf16(a1, B1[ks][2], acc11, 0, 0, 0);
            acc11 = __builtin_amdgcn_mfma_f32_16x16x32_bf16(a1, B1[ks][3], acc11, 0, 0, 0);
        }

        __syncthreads();   // all waves done with hsH readers of previous tile

        // ---- bias + ReLU -> RNE bf16 h into LDS
        {
            int c0 = o0;
            int c1 = o1;
#pragma unroll
            for (int q = 0; q < 4; ++q) {
                int r0 = qr + q;
                int r1 = 16 + qr + q;
                hsH[r0 * H_STR + c0] = f2bf_rne(fmaxf(acc00[q] + bb0, 0.f));
                hsH[r0 * H_STR + c1] = f2bf_rne(fmaxf(acc01[q] + bb1, 0.f));
                hsH[r1 * H_STR + c0] = f2bf_rne(fmaxf(acc10[q] + bb0, 0.f));
                hsH[r1 * H_STR + c1] = f2bf_rne(fmaxf(acc11[q] + bb1, 0.f));
            }
        }
        __syncthreads();

        // ---- GEMM2: hw[32x64] = h[32x128] @ Wg^T
        float4v acc2_0 = {0.f, 0.f, 0.f, 0.f};
        float4v acc2_1 = {0.f, 0.f, 0.f, 0.f};
#pragma unroll
        for (int ks = 0; ks < 4; ++ks) {
            int kb = ks * 32 + lk8;
            short8v a0 = *(const short8v*)&hsH[lrow * H_STR + kb];
            short8v a1 = *(const short8v*)&hsH[(16 + lrow) * H_STR + kb];
            acc2_0 = __builtin_amdgcn_mfma_f32_16x16x32_bf16(a0, B2[ks][0], acc2_0, 0, 0, 0);
            acc2_0 = __builtin_amdgcn_mfma_f32_16x16x32_bf16(a0, B2[ks][1], acc2_0, 0, 0, 0);
            acc2_1 = __builtin_amdgcn_mfma_f32_16x16x32_bf16(a1, B2[ks][0], acc2_1, 0, 0, 0);
            acc2_1 = __builtin_amdgcn_mfma_f32_16x16x32_bf16(a1, B2[ks][1], acc2_1, 0, 0, 0);
        }

        // ---- write hw as RNE bf16, dense N x 64
#pragma unroll
        for (int q = 0; q < 4; ++q) {
            int node0 = nb + qr + q;
            int node1 = nb + 16 + qr + q;
            if (node0 < N) hwbf[(size_t)node0 * DOUT + og] = f2bf_rne(acc2_0[q]);
            if (node1 < N) hwbf[(size_t)node1 * DOUT + og] = f2bf_rne(acc2_1[q]);
        }
    }
}

// ---------------- gather GCN + fused softmax (one wave per node) -----------
__global__ void gather_gcn_softmax(const int* __restrict__ rowptr, const int* __restrict__ col,
                                   const unsigned short* __restrict__ hwbf,
                                   const float* __restrict__ dinv,
                                   const float* __restrict__ bg,
                                   float* __restrict__ out, float* __restrict__ soft, int N) {
    int node = blockIdx.x * 4 + (threadIdx.x >> 6);
    if (node >= N) return;
    int lane = threadIdx.x & 63;
    int half = lane >> 5;
    int hl = lane & 31;
    int beg = rowptr[node], end = rowptr[node + 1];
    float accx = 0.f, accy = 0.f;
    int e = beg;
    for (; e + 7 < end; e += 8) {   // 4 rows in flight per half-wave
        int s0 = col[e + half];
        int s1 = col[e + 2 + half];
        int s2 = col[e + 4 + half];
        int s3 = col[e + 6 + half];
        float w0 = dinv[s0], w1 = dinv[s1], w2 = dinv[s2], w3 = dinv[s3];
        ushort2v v0 = *(const ushort2v*)(hwbf + (size_t)s0 * DOUT + hl * 2);
        ushort2v v1 = *(const ushort2v*)(hwbf + (size_t)s1 * DOUT + hl * 2);
        ushort2v v2 = *(const ushort2v*)(hwbf + (size_t)s2 * DOUT + hl * 2);
        ushort2v v3 = *(const ushort2v*)(hwbf + (size_t)s3 * DOUT + hl * 2);
        accx += w0 * bf2f(v0[0]) + w1 * bf2f(v1[0]) + w2 * bf2f(v2[0]) + w3 * bf2f(v3[0]);
        accy += w0 * bf2f(v0[1]) + w1 * bf2f(v1[1]) + w2 * bf2f(v2[1]) + w3 * bf2f(v3[1]);
    }
    for (; e + 3 < end; e += 4) {
        int s0 = col[e + half];
        int s1 = col[e + 2 + half];
        float w0 = dinv[s0], w1 = dinv[s1];
        ushort2v v0 = *(const ushort2v*)(hwbf + (size_t)s0 * DOUT + hl * 2);
        ushort2v v1 = *(const ushort2v*)(hwbf + (size_t)s1 * DOUT + hl * 2);
        accx += w0 * bf2f(v0[0]) + w1 * bf2f(v1[0]);
        accy += w0 * bf2f(v0[1]) + w1 * bf2f(v1[1]);
    }
    for (; e + 1 < end; e += 2) {
        int s0 = col[e + half];
        float w0 = dinv[s0];
        ushort2v v0 = *(const ushort2v*)(hwbf + (size_t)s0 * DOUT + hl * 2);
        accx += w0 * bf2f(v0[0]);
        accy += w0 * bf2f(v0[1]);
    }
    if (e < end && half == 0) {
        int s0 = col[e];
        float w0 = dinv[s0];
        ushort2v v0 = *(const ushort2v*)(hwbf + (size_t)s0 * DOUT + hl * 2);
        accx += w0 * bf2f(v0[0]);
        accy += w0 * bf2f(v0[1]);
    }
    accx += __shfl_xor(accx, 32, 64);
    accy += __shfl_xor(accy, 32, 64);

    float di = dinv[node];
    ushort2v selfv = *(const ushort2v*)(hwbf + (size_t)node * DOUT + hl * 2);
    float v0 = di * accx + di * di * bf2f(selfv[0]) + bg[hl * 2 + 0];
    float v1 = di * accy + di * di * bf2f(selfv[1]) + bg[hl * 2 + 1];

    float m = fmaxf(v0, v1);
#pragma unroll
    for (int mask = 16; mask; mask >>= 1) m = fmaxf(m, __shfl_xor(m, mask, 64));
    float e0 = __expf(v0 - m), e1 = __expf(v1 - m);
    float s = e0 + e1;
#pragma unroll
    for (int mask = 16; mask; mask >>= 1) s += __shfl_xor(s, mask, 64);
    if (half == 0) {
        float2 ov = make_float2(v0, v1);
        float2 sv = make_float2(e0 / s, e1 / s);
        *(float2*)(out + (size_t)node * DOUT + hl * 2) = ov;
        *(float2*)(soft + (size_t)node * DOUT + hl * 2) = sv;
    }
}

// ---------------------------------------------------------------------------
extern "C" void kernel_launch(void* const* d_in, const int* in_sizes, int n_in,
                              void* d_out, int out_size, void* d_ws, size_t ws_size,
                              hipStream_t stream) {
    const float* x  = (const float*)d_in[0];
    const void*  ei = d_in[1];
    const float* Wl = (const float*)d_in[2];
    const float* bl = (const float*)d_in[3];
    const float* Wr = (const float*)d_in[4];
    const float* Wg = (const float*)d_in[5];
    const float* bg = (const float*)d_in[6];
    const int N = in_sizes[0] / DIN;
    const int E = in_sizes[1] / 2;
    float* out = (float*)d_out;

    char* ws = (char*)d_ws;
    size_t off = 0;
    auto alloc = [&](size_t bytes) {
        void* p = ws + off;
        off += (bytes + 255) / 256 * 256;
        return p;
    };
    int*   flag    = (int*)alloc(4);
    int*   deg     = (int*)alloc((size_t)N * 4);
    float* dinv    = (float*)alloc((size_t)N * 4);
    int*   rowptr  = (int*)alloc((size_t)(N + 1) * 4);
    int*   cursor  = (int*)alloc((size_t)N * 4);
    int*   colv    = (int*)alloc((size_t)E * 4);
    int*   partial = (int*)alloc(1024 * 4);
    unsigned short* WcH = (unsigned short*)alloc(128 * 256 * 2);
    unsigned short* WcL = (unsigned short*)alloc(128 * 256 * 2);
    unsigned short* WgH = (unsigned short*)alloc(64 * 128 * 2);
    unsigned short* WgL = (unsigned short*)alloc(64 * 128 * 2);
    unsigned short* xbf    = (unsigned short*)alloc((size_t)N * DIN * 2);
    unsigned short* meanbf = (unsigned short*)alloc((size_t)N * DIN * 2);
    unsigned short* hwbf   = (unsigned short*)alloc((size_t)N * DOUT * 2);
    (void)ws_size; (void)n_in; (void)out_size;

    float* soft = out + (size_t)N * DOUT;

    const int nblk = (N + 1023) / 1024;

    hipMemsetAsync(deg, 0, (size_t)N * 4, stream);

    detect_idx_kernel<<<1, 256, 0, stream>>>(ei, 2 * E, flag);
    {
        size_t xElems = (size_t)N * DIN;
        size_t total = 128 * 256 + 64 * 128 + (xElems + 3) / 4;
        prep_all<<<(int)((total + 255) / 256), 256, 0, stream>>>(
            Wl, Wr, Wg, WcH, WcL, WgH, WgL, x, xbf, xElems);
    }
    count_deg<<<(E + 255) / 256, 256, 0, stream>>>(ei, flag, deg, E);
    scan_partial<<<nblk, 256, 0, stream>>>(deg, partial, N);
    scan_offsets<<<1, 64, 0, stream>>>(partial, nblk, rowptr, N, E);
    scan_final<<<nblk, 256, 0, stream>>>(deg, partial, rowptr, cursor, dinv, N);
    fill_csr<<<(E + 255) / 256, 256, 0, stream>>>(ei, flag, cursor, colv, E);
    gather_mean<<<(N + 3) / 4, 256, 0, stream>>>(rowptr, colv, xbf, meanbf, N);
    sage_gemm<<<(N + 63) / 64, 256, 0, stream>>>(meanbf, xbf, WcH, WcL, WgH, WgL, bl, hwbf, N);
    gather_gcn_softmax<<<(N + 3) / 4, 256, 0, stream>>>(rowptr, colv, hwbf, dinv, bg, out, soft, N);
}